// Round 8
// baseline (3335.403 us; speedup 1.0000x reference)
//
#include <hip/hip_runtime.h>

// 2-layer LSTM (B=256, T=1024, H=256, IN=1) inference; out = h_n[2,256,256], c_n[2,256,256] f32.
//
// v8: LAYER-SPLIT. 512 WGs x 256 thr (2 WG/CU): WGs 0-255 compute layer 0 only (the tight
// recurrence), WGs 256-511 compute layer 1 (runs 1 step behind, full-step slack).
// L0 critical cycle per step: poll flags -> DIRECT per-lane L2 loads of MFMA B-fragments
// (no LDS, no barrier, waves fully independent) -> 8 MFMA -> lane-local cell update ->
// publish h0 (WG-scope stores stay dirty in same-XCD L2) -> vmcnt(0) -> flag0.
// L0 gates on flag1 >= s-1 (overwrite safety for the 2-deep h0 slots); L1 gates on
// flag0 >= t+1 and flag1 >= t. Flag set strictly after vmcnt(0) drains both this step's
// fetch-loads and data-stores -> release semantics within the XCD L2.
// L0 waves run at s_setprio(1); L1 spins with s_sleep backoff (slack absorbs it).
// Runtime XCC_ID handshake validates same-XCD placement; agent-scope mirror fallback else.
// Windowed flag compare (f - want < 2^16) rejects 0xAA poison -> no ws init needed.

#define TSTEPS 1024u
#define FMAGIC 0x5A5A0000u

typedef __attribute__((ext_vector_type(8))) short bf16x8;
typedef __attribute__((ext_vector_type(4))) float f32x4;

__device__ __forceinline__ unsigned short f2bf(float f) {
  unsigned u = __float_as_uint(f);
  u += 0x7FFFu + ((u >> 16) & 1u);   // RNE
  return (unsigned short)(u >> 16);
}
__device__ __forceinline__ float sigm(float x) { return 1.0f / (1.0f + __expf(-x)); }
__device__ __forceinline__ float tanh_f(float x) {
  float xc = fminf(fmaxf(x, -15.0f), 15.0f);
  float e = __expf(2.0f * xc);
  return (e - 1.0f) / (e + 1.0f);
}

union FragU { unsigned long long q[2]; bf16x8 v; };

__global__ __launch_bounds__(256, 2) void lstm2_v8(
    const float* __restrict__ x,     // [256][1024]
    const float* __restrict__ Wih0,  // [1024][1]
    const float* __restrict__ Whh0,  // [1024][256]
    const float* __restrict__ bih0, const float* __restrict__ bhh0,
    const float* __restrict__ Wih1,  // [1024][256]
    const float* __restrict__ Whh1,  // [1024][256]
    const float* __restrict__ bih1, const float* __restrict__ bhh1,
    float* __restrict__ out,                      // [4][256][256]
    unsigned long long* __restrict__ fastb,       // [2 slots][16c][2L][16row][64q] u64 = 512KB
    unsigned long long* __restrict__ slowb,       // mirror (agent-coherent fallback)
    unsigned* __restrict__ ctrl,                  // [512] xcc slots + [16] decisions
    unsigned* __restrict__ flagF,                 // [16c][2][64] flags (flag0, flag1)
    unsigned* __restrict__ flagS)                 // mirror flags
{
  const int bid  = blockIdx.x;   // 512 WGs; cluster c WGs all == c (mod 8) -> one XCD
  const int type = bid >> 8;     // 0 = layer0, 1 = layer1
  const int c    = bid & 15;
  const int iw   = (bid >> 4) & 15;   // j-block of 16 gate-cols per wave-set
  const int tid  = threadIdx.x;
  const int lane = tid & 63;
  const int wv   = tid >> 6;     // wave 0..3
  const int hi   = lane >> 4;    // 0..3
  const int lm   = lane & 15;

  // ---- publish my XCD id (agent scope)
  unsigned myxcc;
  asm volatile("s_getreg_b32 %0, hwreg(HW_REG_XCC_ID)" : "=s"(myxcc));
  myxcc &= 0xFu;
  if (tid == 0)
    __hip_atomic_store(&ctrl[bid], FMAGIC | myxcc,
                       __ATOMIC_RELAXED, __HIP_MEMORY_SCOPE_AGENT);

  // ---- register-resident weight A-operand fragments (swapped-operand: col m = jl*4+gate)
  bf16x8 wA[8], wB[8];
  {
    const int wrow = (lm & 3) * 256 + (iw << 4) + (wv << 2) + (lm >> 2);
    const int kb   = hi << 3;
    if (type == 0) {
      const float* pA = Whh0 + (size_t)wrow * 256 + kb;
#pragma unroll
      for (int kk = 0; kk < 8; ++kk) {
        bf16x8 a;
#pragma unroll
        for (int e = 0; e < 8; ++e) a[e] = (short)f2bf(pA[kk * 32 + e]);
        wA[kk] = a;
      }
    } else {
      const float* pA = Wih1 + (size_t)wrow * 256 + kb;
      const float* pB = Whh1 + (size_t)wrow * 256 + kb;
#pragma unroll
      for (int kk = 0; kk < 8; ++kk) {
        bf16x8 a, b;
#pragma unroll
        for (int e = 0; e < 8; ++e) {
          a[e] = (short)f2bf(pA[kk * 32 + e]);
          b[e] = (short)f2bf(pB[kk * 32 + e]);
        }
        wA[kk] = a; wB[kk] = b;
      }
    }
  }

  // ---- lane-local elementwise constants (element: batch row lm, hidden col jg)
  const int rowE = lm;
  const int jg   = (iw << 4) + (wv << 2) + hi;
  float wx[4], bs[4];
#pragma unroll
  for (int r = 0; r < 4; ++r) {
    const int col = (r << 8) + jg;
    if (type == 0) { wx[r] = Wih0[col]; bs[r] = bih0[col] + bhh0[col]; }
    else           { wx[r] = 0.f;       bs[r] = bih1[col] + bhh1[col]; }
  }

  // ---- XCD uniformity handshake (L0 WG iw==0 decides for the 32 WGs of its cluster)
  __shared__ unsigned s_uni;
  if (tid == 0) {
    if (type == 0 && iw == 0) {
      unsigned x0 = 0, uni = 1u;
      for (int k = 0; k < 32 && uni; ++k) {
        const int b2 = (k < 16) ? (c + 16 * k) : (256 + c + 16 * (k - 16));
        unsigned v; int g2 = 0;
        for (;;) {
          v = __hip_atomic_load(&ctrl[b2], __ATOMIC_RELAXED, __HIP_MEMORY_SCOPE_AGENT);
          if ((v & 0xFFFF0000u) == FMAGIC) break;
          if (++g2 > (1 << 15)) { uni = 0u; break; }
        }
        if (uni) {
          const unsigned xc = v & 0xFFFFu;
          if (k == 0) x0 = xc; else if (xc != x0) uni = 0u;
        }
      }
      __hip_atomic_store(&ctrl[512 + c], FMAGIC | uni,
                         __ATOMIC_RELAXED, __HIP_MEMORY_SCOPE_AGENT);
    }
    unsigned uni = 0u; int g2 = 0;
    for (;;) {
      unsigned v = __hip_atomic_load(&ctrl[512 + c], __ATOMIC_RELAXED, __HIP_MEMORY_SCOPE_AGENT);
      if ((v & 0xFFFF0000u) == FMAGIC) { uni = v & 1u; break; }
      if (++g2 > (1 << 15)) break;
    }
    s_uni = uni;
  }
  __syncthreads();
  const bool uniform = (s_uni != 0u);
  unsigned long long* pollD = uniform ? fastb : slowb;
  unsigned*           pollF = uniform ? flagF : flagS;
  unsigned*           flc   = pollF + c * 128;            // [flag0 x64][flag1 x64]

  const size_t oBase = (size_t)((c << 4) + rowE) * 256 + jg;
  bool dead = false;

  if (type == 0) {
    // =================== LAYER 0: the tight recurrence (LDS-free) ===================
    __builtin_amdgcn_s_setprio(1);
    unsigned* myF = &flagF[c * 128 + (iw << 2) + wv];
    unsigned* myS = &flagS[c * 128 + (iw << 2) + wv];
    const float* xrow = x + (size_t)((c << 4) + rowE) * TSTEPS;
    float4 xq = {0.f, 0.f, 0.f, 0.f};
    float c0 = 0.f, h0f = 0.f;

    for (unsigned s = 0; s < TSTEPS; ++s) {
      if ((s & 3u) == 0u) xq = *(const float4*)(xrow + s);
      const float xv = (s & 2u) ? ((s & 1u) ? xq.w : xq.z) : ((s & 1u) ? xq.y : xq.x);

      // ---- acquire h0[s-1] fragments directly from L2 (no LDS, no barrier)
      bf16x8 af0[8];
      if (s == 0) {
        const bf16x8 z = {0, 0, 0, 0, 0, 0, 0, 0};
#pragma unroll
        for (int kk = 0; kk < 8; ++kk) af0[kk] = z;
      } else {
        const unsigned want0 = FMAGIC + s;
        const unsigned want1 = FMAGIC + s - 1u;
        const bool chk1 = (s >= 2u);
        int guard = 0;
        while (!dead) {
          const unsigned f0 = __hip_atomic_load(flc + lane, __ATOMIC_RELAXED, __HIP_MEMORY_SCOPE_AGENT);
          const unsigned f1 = chk1 ? __hip_atomic_load(flc + 64 + lane, __ATOMIC_RELAXED, __HIP_MEMORY_SCOPE_AGENT)
                                   : want1;
          const bool ok = ((f0 - want0) < 0x10000u) & ((f1 - want1) < 0x10000u);
          if (__all(ok)) break;
          if (++guard > (1 << 13)) dead = true;   // sticky bailout: fail visibly, never hang
        }
        // frag layout: row = lm, bytes hi*16 + kk*64 within the 512B row
        const unsigned long long* hb =
            pollD + (size_t)(s & 1u) * 32768u + (c << 11) + (lm << 6) + (hi << 1);
#pragma unroll
        for (int kk = 0; kk < 8; ++kk) {
          FragU u;
          u.q[0] = __hip_atomic_load(hb + kk * 8,     __ATOMIC_RELAXED, __HIP_MEMORY_SCOPE_AGENT);
          u.q[1] = __hip_atomic_load(hb + kk * 8 + 1, __ATOMIC_RELAXED, __HIP_MEMORY_SCOPE_AGENT);
          af0[kk] = u.v;
        }
      }

      // ---- 8 MFMA, 2 split chains
      f32x4 aca = {0.f, 0.f, 0.f, 0.f}, acb = {0.f, 0.f, 0.f, 0.f};
#pragma unroll
      for (int kk = 0; kk < 4; ++kk)
        aca = __builtin_amdgcn_mfma_f32_16x16x32_bf16(wA[kk], af0[kk], aca, 0, 0, 0);
#pragma unroll
      for (int kk = 4; kk < 8; ++kk)
        acb = __builtin_amdgcn_mfma_f32_16x16x32_bf16(wA[kk], af0[kk], acb, 0, 0, 0);

      // ---- lane-local cell update (acc[r] = gate r)
      const float pi = (aca[0] + acb[0]) + xv * wx[0] + bs[0];
      const float pf = (aca[1] + acb[1]) + xv * wx[1] + bs[1];
      const float pg = (aca[2] + acb[2]) + xv * wx[2] + bs[2];
      const float po = (aca[3] + acb[3]) + xv * wx[3] + bs[3];
      const float ig = sigm(pi), fg = sigm(pf), gv = tanh_f(pg), og = sigm(po);
      c0  = fg * c0 + ig * gv;
      h0f = og * tanh_f(c0);

      // ---- publish h0[s] into slot (s+1)&1
      const int v   = (int)(unsigned)f2bf(h0f);
      const int p16 = __shfl_xor(v, 16);
      const unsigned part = (unsigned)(unsigned short)v | ((unsigned)(unsigned short)p16 << 16);
      const unsigned p32  = (unsigned)__shfl_xor((int)part, 32);
      const unsigned long long v64 = (unsigned long long)part | ((unsigned long long)p32 << 32);
      const unsigned i0 = ((c * 2 + 0) * 16 + (unsigned)rowE) * 64 + (unsigned)((iw << 2) + wv);
      unsigned long long* fb = fastb + (size_t)((s + 1u) & 1u) * 32768u;
      unsigned long long* sb = slowb + (size_t)((s + 1u) & 1u) * 32768u;
      if (hi == 0) {
        __hip_atomic_store(fb + i0, v64, __ATOMIC_RELAXED, __HIP_MEMORY_SCOPE_WORKGROUP);
        if (!uniform)
          __hip_atomic_store(sb + i0, v64, __ATOMIC_RELAXED, __HIP_MEMORY_SCOPE_AGENT);
      }
      asm volatile("s_waitcnt vmcnt(0)" ::: "memory");   // drain store AND this step's loads
      if (lane == 0) {
        const unsigned fv = FMAGIC + s + 1u;
        if (uniform)
          __hip_atomic_store(myF, fv, __ATOMIC_RELAXED, __HIP_MEMORY_SCOPE_WORKGROUP);
        else
          __hip_atomic_store(myS, fv, __ATOMIC_RELAXED, __HIP_MEMORY_SCOPE_AGENT);
      }
    }
    out[oBase]          = h0f;   // h_n layer 0
    out[131072 + oBase] = c0;    // c_n layer 0

  } else {
    // =================== LAYER 1: one step behind, slack-tolerant ===================
    unsigned* myF = &flagF[c * 128 + 64 + (iw << 2) + wv];
    unsigned* myS = &flagS[c * 128 + 64 + (iw << 2) + wv];

    unsigned ofs_[8], lofs_[8];
#pragma unroll
    for (int i = 0; i < 8; ++i) {
      const int n   = tid + 256 * i;
      const int L   = n >> 10;
      const int row = (n >> 6) & 15;
      const int q   = n & 63;
      ofs_[i]  = (unsigned)(((c * 2 + L) * 16 + row) * 64 + q);
      lofs_[i] = (unsigned)(L * 4224 + row * 264 + q * 4);
    }

    __shared__ __align__(16) unsigned short A[2 * 2 * 16 * 264];  // [parity][L][row][264]
    for (int z = tid; z < 8448; z += 256) ((unsigned*)A)[z] = 0u;
    __syncthreads();

    float c1 = 0.f, h1f = 0.f;

    for (unsigned t = 0; t < TSTEPS; ++t) {
      // ---- poll: h0[t] ready (flag0 >= t+1) and h1[t-1] ready (flag1 >= t)
      {
        const unsigned want0 = FMAGIC + t + 1u;
        const unsigned want1 = FMAGIC + t;
        const bool chk1 = (t >= 1u);
        int guard = 0;
        while (!dead) {
          const unsigned f0 = __hip_atomic_load(flc + lane, __ATOMIC_RELAXED, __HIP_MEMORY_SCOPE_AGENT);
          const unsigned f1 = chk1 ? __hip_atomic_load(flc + 64 + lane, __ATOMIC_RELAXED, __HIP_MEMORY_SCOPE_AGENT)
                                   : want1;
          const bool ok = ((f0 - want0) < 0x10000u) & ((f1 - want1) < 0x10000u);
          if (__all(ok)) break;
          if (++guard > (1 << 13)) { dead = true; break; }
          __builtin_amdgcn_s_sleep(1);   // slack-tolerant backoff
        }
      }
      // ---- fetch h0[t] (slot (t+1)&1, L=0) and h1[t-1] (slot t&1, L=1); stage to parity LDS
      const unsigned long long* pb0 = pollD + (size_t)((t + 1u) & 1u) * 32768u;
      const unsigned long long* pb1 = pollD + (size_t)(t & 1u) * 32768u;
      unsigned short* Ap = A + (t & 1u) * 8448u;
      {
        unsigned long long vv[8];
#pragma unroll
        for (int i = 0; i < 4; ++i)
          vv[i] = __hip_atomic_load(pb0 + ofs_[i], __ATOMIC_RELAXED, __HIP_MEMORY_SCOPE_AGENT);
        if (t >= 1u) {
#pragma unroll
          for (int i = 4; i < 8; ++i)
            vv[i] = __hip_atomic_load(pb1 + ofs_[i], __ATOMIC_RELAXED, __HIP_MEMORY_SCOPE_AGENT);
        }
#pragma unroll
        for (int i = 0; i < 4; ++i)
          *(unsigned long long*)&Ap[lofs_[i]] = vv[i];
        if (t >= 1u) {
#pragma unroll
          for (int i = 4; i < 8; ++i)
            *(unsigned long long*)&Ap[lofs_[i]] = vv[i];
        }
      }
      __syncthreads();   // one barrier per step (parity buffers)

      // ---- 16 MFMA: Wih1*h0[t] + Whh1*h1[t-1]
      const unsigned short* a0p = Ap + lm * 264 + (hi << 3);
      const unsigned short* a1p = a0p + 4224;
      f32x4 p0 = {0.f,0.f,0.f,0.f}, p1 = {0.f,0.f,0.f,0.f};
      f32x4 q0 = {0.f,0.f,0.f,0.f}, q1 = {0.f,0.f,0.f,0.f};
#pragma unroll
      for (int kk = 0; kk < 4; ++kk) {
        p0 = __builtin_amdgcn_mfma_f32_16x16x32_bf16(wA[kk], *(const bf16x8*)(a0p + kk * 32), p0, 0, 0, 0);
        q0 = __builtin_amdgcn_mfma_f32_16x16x32_bf16(wB[kk], *(const bf16x8*)(a1p + kk * 32), q0, 0, 0, 0);
      }
#pragma unroll
      for (int kk = 4; kk < 8; ++kk) {
        p1 = __builtin_amdgcn_mfma_f32_16x16x32_bf16(wA[kk], *(const bf16x8*)(a0p + kk * 32), p1, 0, 0, 0);
        q1 = __builtin_amdgcn_mfma_f32_16x16x32_bf16(wB[kk], *(const bf16x8*)(a1p + kk * 32), q1, 0, 0, 0);
      }

      // ---- lane-local cell update
      const float pi = (p0[0] + p1[0]) + (q0[0] + q1[0]) + bs[0];
      const float pf = (p0[1] + p1[1]) + (q0[1] + q1[1]) + bs[1];
      const float pg = (p0[2] + p1[2]) + (q0[2] + q1[2]) + bs[2];
      const float po = (p0[3] + p1[3]) + (q0[3] + q1[3]) + bs[3];
      const float ig = sigm(pi), fg = sigm(pf), gv = tanh_f(pg), og = sigm(po);
      c1  = fg * c1 + ig * gv;
      h1f = og * tanh_f(c1);

      // ---- publish h1[t] into slot (t+1)&1, L=1
      const int v   = (int)(unsigned)f2bf(h1f);
      const int p16 = __shfl_xor(v, 16);
      const unsigned part = (unsigned)(unsigned short)v | ((unsigned)(unsigned short)p16 << 16);
      const unsigned p32  = (unsigned)__shfl_xor((int)part, 32);
      const unsigned long long v64 = (unsigned long long)part | ((unsigned long long)p32 << 32);
      const unsigned i1 = ((c * 2 + 1) * 16 + (unsigned)rowE) * 64 + (unsigned)((iw << 2) + wv);
      unsigned long long* fb = fastb + (size_t)((t + 1u) & 1u) * 32768u;
      unsigned long long* sb = slowb + (size_t)((t + 1u) & 1u) * 32768u;
      if (hi == 0) {
        __hip_atomic_store(fb + i1, v64, __ATOMIC_RELAXED, __HIP_MEMORY_SCOPE_WORKGROUP);
        if (!uniform)
          __hip_atomic_store(sb + i1, v64, __ATOMIC_RELAXED, __HIP_MEMORY_SCOPE_AGENT);
      }
      asm volatile("s_waitcnt vmcnt(0)" ::: "memory");   // drain fetch-loads AND store
      if (lane == 0) {
        const unsigned fv = FMAGIC + t + 1u;
        if (uniform)
          __hip_atomic_store(myF, fv, __ATOMIC_RELAXED, __HIP_MEMORY_SCOPE_WORKGROUP);
        else
          __hip_atomic_store(myS, fv, __ATOMIC_RELAXED, __HIP_MEMORY_SCOPE_AGENT);
      }
    }
    out[65536 + oBase]          = h1f;   // h_n layer 1
    out[131072 + 65536 + oBase] = c1;    // c_n layer 1
  }
}

extern "C" void kernel_launch(void* const* d_in, const int* in_sizes, int n_in,
                              void* d_out, int out_size, void* d_ws, size_t ws_size,
                              hipStream_t stream) {
  const float* x    = (const float*)d_in[0];
  const float* Wih0 = (const float*)d_in[1];
  const float* Whh0 = (const float*)d_in[2];
  const float* bih0 = (const float*)d_in[3];
  const float* bhh0 = (const float*)d_in[4];
  const float* Wih1 = (const float*)d_in[5];
  const float* Whh1 = (const float*)d_in[6];
  const float* bih1 = (const float*)d_in[7];
  const float* bhh1 = (const float*)d_in[8];

  unsigned long long* fastb = (unsigned long long*)d_ws;
  unsigned long long* slowb;
  unsigned *ctrl, *flagF, *flagS;
  if (ws_size >= (1u << 20) + 24576u) {
    slowb = fastb + 65536;                      // @512KB
    ctrl  = (unsigned*)(fastb + 131072);        // @1MB      (528 u32 used, 8KB reserved)
    flagF = ctrl + 2048;                        // @1MB+8KB  (2048 u32)
    flagS = flagF + 2048;                       // @1MB+16KB (2048 u32)
  } else {                                      // compact fallback (uniform path unaffected)
    slowb = fastb;
    ctrl  = (unsigned*)((char*)d_ws + (512u << 10));
    flagF = ctrl + 2048;
    flagS = flagF;
  }

  lstm2_v8<<<512, 256, 0, stream>>>(x, Wih0, Whh0, bih0, bhh0,
                                    Wih1, Whh1, bih1, bhh1,
                                    (float*)d_out, fastb, slowb, ctrl, flagF, flagS);
}

// Round 9
// 1878.072 us; speedup vs baseline: 1.7760x; 1.7760x over previous
//
#include <hip/hip_runtime.h>

// 2-layer LSTM (B=256, T=1024, H=256, IN=1) inference; out = h_n[2,256,256], c_n[2,256,256] f32.
//
// v9 = v7 topology (16 clusters x 16 WGs x 256 thr, register-resident weights as MFMA A-operand,
// lane-local cell updates, merged poll, ONE barrier/step, parity LDS) with the critical cycle cut:
//  1. x pre-staged in LDS (stride 1041, conflict-free) -> NO HBM ops in the loop; the per-step
//     vmcnt(0) drains only the h store (~200cy) instead of a ~900cy HBM x-load.
//  2. SPLIT release flags: flagH0 stored right after h0 store+drain (before ANY layer-1 work);
//     the layer-1 tail (16 MFMA + elem1 + h1 publish + flagH1) runs in the consumers' slack.
//     Overwrite safety: flagH0 is set after the same-step fetch, so "all flagH0 >= s+2" still
//     gates every slot overwrite (same induction as v7).
//  3. Single-shuffle u32 publish (xor16 pairs cols hi<->hi+1; 32 lanes store u32) -- byte-identical
//     layout to the u64 chunk format consumers fetch.
// Exchange: WORKGROUP-scope stores stay dirty in the same-XCD L2 (runtime XCC_ID handshake);
// agent-scope mirror fallback if placement non-uniform. Windowed flag compare rejects 0xAA
// poison -> no ws init needed. Sticky guard bailout -> never hangs.

#define TSTEPS 1024u
#define FMAGIC 0x5A5A0000u

typedef __attribute__((ext_vector_type(8))) short bf16x8;
typedef __attribute__((ext_vector_type(4))) float f32x4;

__device__ __forceinline__ unsigned short f2bf(float f) {
  unsigned u = __float_as_uint(f);
  u += 0x7FFFu + ((u >> 16) & 1u);   // RNE
  return (unsigned short)(u >> 16);
}
__device__ __forceinline__ float sigm(float x) { return 1.0f / (1.0f + __expf(-x)); }
__device__ __forceinline__ float tanh_f(float x) {
  float xc = fminf(fmaxf(x, -15.0f), 15.0f);
  float e = __expf(2.0f * xc);
  return (e - 1.0f) / (e + 1.0f);
}

__global__ __launch_bounds__(256, 1) void lstm2_v9(
    const float* __restrict__ x,     // [256][1024]
    const float* __restrict__ Wih0,  // [1024][1]
    const float* __restrict__ Whh0,  // [1024][256]
    const float* __restrict__ bih0, const float* __restrict__ bhh0,
    const float* __restrict__ Wih1,  // [1024][256]
    const float* __restrict__ Whh1,  // [1024][256]
    const float* __restrict__ bih1, const float* __restrict__ bhh1,
    float* __restrict__ out,                      // [4][256][256]
    unsigned long long* __restrict__ fastb,       // [2 slots][16c][2L][16row][64q] u64 = 512KB
    unsigned long long* __restrict__ slowb,       // mirror (agent-coherent fallback)
    unsigned* __restrict__ ctrl,                  // [256] xcc slots + [16] decisions
    unsigned* __restrict__ flagF,                 // [16c][2][64]: flagH0 x64, flagH1 x64
    unsigned* __restrict__ flagS)                 // mirror flags
{
  const int bid  = blockIdx.x;   // 256 WGs; cluster c = bid&15 -> WGs {c, c+16, ...}: one XCD
  const int c    = bid & 15;
  const int iw   = bid >> 4;     // 0..15: j-block of 16 hidden cols
  const int tid  = threadIdx.x;
  const int lane = tid & 63;
  const int wv   = tid >> 6;     // wave 0..3
  const int hi   = lane >> 4;    // 0..3
  const int lm   = lane & 15;    // batch row (lane-local element)

  // ---- publish my XCD id (agent scope)
  unsigned myxcc;
  asm volatile("s_getreg_b32 %0, hwreg(HW_REG_XCC_ID)" : "=s"(myxcc));
  myxcc &= 0xFu;
  if (tid == 0)
    __hip_atomic_store(&ctrl[bid], FMAGIC | myxcc,
                       __ATOMIC_RELAXED, __HIP_MEMORY_SCOPE_AGENT);

  // ---- weight A-operand fragments (swapped-operand; tile col m = jl*4 + gate)
  bf16x8 w0[8], wi1[8], wh1[8];
  {
    const int wrow = (lm & 3) * 256 + (iw << 4) + (wv << 2) + (lm >> 2);
    const int kb   = hi << 3;
#pragma unroll
    for (int kk = 0; kk < 8; ++kk) {
      const int k0 = kk * 32 + kb;
      const float* p0 = Whh0 + (size_t)wrow * 256 + k0;
      const float* p1 = Wih1 + (size_t)wrow * 256 + k0;
      const float* p2 = Whh1 + (size_t)wrow * 256 + k0;
      bf16x8 a, b, cc;
#pragma unroll
      for (int e = 0; e < 8; ++e) {
        a[e]  = (short)f2bf(p0[e]);
        b[e]  = (short)f2bf(p1[e]);
        cc[e] = (short)f2bf(p2[e]);
      }
      w0[kk] = a; wi1[kk] = b; wh1[kk] = cc;
    }
  }

  // ---- lane-local elementwise constants
  const int jg = (iw << 4) + (wv << 2) + hi;
  float wx[4], bs0[4], bs1[4];
#pragma unroll
  for (int r = 0; r < 4; ++r) {
    const int col = (r << 8) + jg;
    wx[r]  = Wih0[col];
    bs0[r] = bih0[col] + bhh0[col];
    bs1[r] = bih1[col] + bhh1[col];
  }

  // ---- LDS: parity-double-buffered A tiles + staged x
  __shared__ __align__(16) unsigned short A[2 * 2 * 16 * 264];  // 33792 B
  __shared__ float XL[16 * 1041];                               // 66624 B (stride 1041: no conflicts)

  // ---- stage x once (coalesced HBM reads); covered by the handshake's __syncthreads
  {
    const float* xsrc = x + (size_t)(c << 4) * TSTEPS;
    for (int idx = tid; idx < 16 * 1024; idx += 256)
      XL[(idx >> 10) * 1041 + (idx & 1023)] = xsrc[idx];
  }

  // ---- fetch slot tables: 8 chunks/thread (L0: i=0..3, L1: i=4..7); q = tid&63 fixed
  unsigned ofs_[8], lofs_[8];
#pragma unroll
  for (int i = 0; i < 8; ++i) {
    const int n   = tid + 256 * i;
    const int L   = n >> 10;
    const int row = (n >> 6) & 15;
    const int q   = n & 63;
    ofs_[i]  = (unsigned)(((c * 2 + L) * 16 + row) * 64 + q);
    lofs_[i] = (unsigned)(L * 4224 + row * 264 + q * 4);
  }

  // ---- XCD uniformity handshake (WG iw==0 of each cluster decides)
  __shared__ unsigned s_uni;
  if (tid == 0) {
    if (iw == 0) {
      unsigned x0 = 0, uni = 1u;
      for (int k = 0; k < 16 && uni; ++k) {
        unsigned v; int g2 = 0;
        for (;;) {
          v = __hip_atomic_load(&ctrl[c + 16 * k], __ATOMIC_RELAXED, __HIP_MEMORY_SCOPE_AGENT);
          if ((v & 0xFFFF0000u) == FMAGIC) break;
          if (++g2 > (1 << 15)) { uni = 0u; break; }
        }
        if (uni) {
          const unsigned xc = v & 0xFFFFu;
          if (k == 0) x0 = xc; else if (xc != x0) uni = 0u;
        }
      }
      __hip_atomic_store(&ctrl[256 + c], FMAGIC | uni,
                         __ATOMIC_RELAXED, __HIP_MEMORY_SCOPE_AGENT);
    }
    unsigned uni = 0u; int g2 = 0;
    for (;;) {
      unsigned v = __hip_atomic_load(&ctrl[256 + c], __ATOMIC_RELAXED, __HIP_MEMORY_SCOPE_AGENT);
      if ((v & 0xFFFF0000u) == FMAGIC) { uni = v & 1u; break; }
      if (++g2 > (1 << 15)) break;
    }
    s_uni = uni;
  }
  __syncthreads();
  const bool uniform = (s_uni != 0u);
  unsigned long long* pollD = uniform ? fastb : slowb;
  unsigned*           pollF = uniform ? flagF : flagS;
  unsigned*           fl    = pollF + c * 128;                 // [flagH0 x64][flagH1 x64]
  unsigned*           myF0F = &flagF[c * 128 + (iw << 2) + wv];
  unsigned*           myF0S = &flagS[c * 128 + (iw << 2) + wv];
  unsigned*           myF1F = myF0F + 64;
  unsigned*           myF1S = myF0S + 64;

  float c0 = 0.f, h0f = 0.f, c1 = 0.f, h1f = 0.f;
  bool dead = false;

  for (unsigned s = 0; s <= TSTEPS; ++s) {
    const unsigned long long* pb = pollD + (size_t)(s & 1u) * 32768u;
    unsigned short* Ap = A + (s & 1u) * 8448u;
    unsigned* fb32 = (unsigned*)(fastb + (size_t)((s + 1u) & 1u) * 32768u);
    unsigned* sb32 = (unsigned*)(slowb + (size_t)((s + 1u) & 1u) * 32768u);

    // ---- phase 1: poll both flags, then single fetch + stage into parity LDS
    if (s == 0) {
      for (int z = tid; z < 8448; z += 256) ((unsigned*)A)[z] = 0u;   // zero both parities
    } else {
      const unsigned want = FMAGIC + s;
      int guard = 0;
      while (!dead) {
        const unsigned f0 = __hip_atomic_load(fl + lane,      __ATOMIC_RELAXED, __HIP_MEMORY_SCOPE_AGENT);
        const unsigned f1 = __hip_atomic_load(fl + 64 + lane, __ATOMIC_RELAXED, __HIP_MEMORY_SCOPE_AGENT);
        if (__all(((f0 - want) < 0x10000u) & ((f1 - want) < 0x10000u))) break;
        if (++guard > (1 << 14)) dead = true;   // sticky bailout: fail visibly, never hang
      }
      unsigned long long vv[8];
#pragma unroll
      for (int i = 0; i < 8; ++i)
        vv[i] = __hip_atomic_load(pb + ofs_[i], __ATOMIC_RELAXED, __HIP_MEMORY_SCOPE_AGENT);
#pragma unroll
      for (int i = 0; i < 8; ++i)
        *(unsigned long long*)&Ap[lofs_[i]] = vv[i];
    }
    __syncthreads();   // the ONE barrier per step

    // ---- phase 2: layer0 MFMA (4 short chains), keep h0 frags for layer1
    bf16x8 af0[8];
    const unsigned short* a0p = Ap + lm * 264 + (hi << 3);
    const unsigned short* a1p = a0p + 4224;
    f32x4 A0 = {0.f,0.f,0.f,0.f}, A1 = {0.f,0.f,0.f,0.f};
    f32x4 A2 = {0.f,0.f,0.f,0.f}, A3 = {0.f,0.f,0.f,0.f};
#pragma unroll
    for (int kk = 0; kk < 8; ++kk) af0[kk] = *(const bf16x8*)(a0p + kk * 32);
    A0 = __builtin_amdgcn_mfma_f32_16x16x32_bf16(w0[0], af0[0], A0, 0, 0, 0);
    A1 = __builtin_amdgcn_mfma_f32_16x16x32_bf16(w0[1], af0[1], A1, 0, 0, 0);
    A2 = __builtin_amdgcn_mfma_f32_16x16x32_bf16(w0[2], af0[2], A2, 0, 0, 0);
    A3 = __builtin_amdgcn_mfma_f32_16x16x32_bf16(w0[3], af0[3], A3, 0, 0, 0);
    A0 = __builtin_amdgcn_mfma_f32_16x16x32_bf16(w0[4], af0[4], A0, 0, 0, 0);
    A1 = __builtin_amdgcn_mfma_f32_16x16x32_bf16(w0[5], af0[5], A1, 0, 0, 0);
    A2 = __builtin_amdgcn_mfma_f32_16x16x32_bf16(w0[6], af0[6], A2, 0, 0, 0);
    A3 = __builtin_amdgcn_mfma_f32_16x16x32_bf16(w0[7], af0[7], A3, 0, 0, 0);

    // ---- phase 3: layer0 cell update + h0 publish + EARLY flagH0
    const float xv = XL[lm * 1041 + (int)(s < TSTEPS ? s : 0u)];
    if (s < TSTEPS) {
      const float pi = (A0[0] + A1[0]) + (A2[0] + A3[0]) + xv * wx[0] + bs0[0];
      const float pf = (A0[1] + A1[1]) + (A2[1] + A3[1]) + xv * wx[1] + bs0[1];
      const float pg = (A0[2] + A1[2]) + (A2[2] + A3[2]) + xv * wx[2] + bs0[2];
      const float po = (A0[3] + A1[3]) + (A2[3] + A3[3]) + xv * wx[3] + bs0[3];
      const float ig = sigm(pi), fg = sigm(pf), gv = tanh_f(pg), og = sigm(po);
      c0  = fg * c0 + ig * gv;
      h0f = og * tanh_f(c0);

      const int v   = (int)(unsigned)f2bf(h0f);
      const int p16 = __shfl_xor(v, 16);          // pair cols hi <-> hi+1
      if ((hi & 1) == 0) {
        const unsigned val = (unsigned)(unsigned short)v |
                             ((unsigned)(unsigned short)p16 << 16);
        const unsigned idx = (unsigned)(((c * 2 + 0) * 16 + lm) * 128 +
                                        (iw << 3) + (wv << 1) + (hi >> 1));
        __hip_atomic_store(fb32 + idx, val, __ATOMIC_RELAXED, __HIP_MEMORY_SCOPE_WORKGROUP);
        if (!uniform)
          __hip_atomic_store(sb32 + idx, val, __ATOMIC_RELAXED, __HIP_MEMORY_SCOPE_AGENT);
      }
      asm volatile("s_waitcnt vmcnt(0)" ::: "memory");   // drains ONLY the h0 store (x is LDS)
      if (lane == 0) {
        const unsigned fv = FMAGIC + s + 1u;
        if (uniform)
          __hip_atomic_store(myF0F, fv, __ATOMIC_RELAXED, __HIP_MEMORY_SCOPE_WORKGROUP);
        else
          __hip_atomic_store(myF0S, fv, __ATOMIC_RELAXED, __HIP_MEMORY_SCOPE_AGENT);
      }
    }

    // ---- phase 4: layer1 MFMA (in consumers' slack)
    f32x4 B0 = {0.f,0.f,0.f,0.f}, B1 = {0.f,0.f,0.f,0.f};
    f32x4 B2 = {0.f,0.f,0.f,0.f}, B3 = {0.f,0.f,0.f,0.f};
#pragma unroll
    for (int kk = 0; kk < 4; ++kk) {
      B0 = __builtin_amdgcn_mfma_f32_16x16x32_bf16(wi1[kk], af0[kk], B0, 0, 0, 0);
      const bf16x8 a1f = *(const bf16x8*)(a1p + kk * 32);
      B1 = __builtin_amdgcn_mfma_f32_16x16x32_bf16(wh1[kk], a1f, B1, 0, 0, 0);
    }
#pragma unroll
    for (int kk = 4; kk < 8; ++kk) {
      B2 = __builtin_amdgcn_mfma_f32_16x16x32_bf16(wi1[kk], af0[kk], B2, 0, 0, 0);
      const bf16x8 a1f = *(const bf16x8*)(a1p + kk * 32);
      B3 = __builtin_amdgcn_mfma_f32_16x16x32_bf16(wh1[kk], a1f, B3, 0, 0, 0);
    }

    // ---- phase 5: layer1 cell update + h1 publish + flagH1
    if (s >= 1u) {
      const float pi = (B0[0] + B1[0]) + (B2[0] + B3[0]) + bs1[0];
      const float pf = (B0[1] + B1[1]) + (B2[1] + B3[1]) + bs1[1];
      const float pg = (B0[2] + B1[2]) + (B2[2] + B3[2]) + bs1[2];
      const float po = (B0[3] + B1[3]) + (B2[3] + B3[3]) + bs1[3];
      const float ig = sigm(pi), fg = sigm(pf), gv = tanh_f(pg), og = sigm(po);
      c1  = fg * c1 + ig * gv;
      h1f = og * tanh_f(c1);
    }
    if (s < TSTEPS) {
      const int v   = (int)(unsigned)f2bf(h1f);
      const int p16 = __shfl_xor(v, 16);
      if ((hi & 1) == 0) {
        const unsigned val = (unsigned)(unsigned short)v |
                             ((unsigned)(unsigned short)p16 << 16);
        const unsigned idx = (unsigned)(((c * 2 + 1) * 16 + lm) * 128 +
                                        (iw << 3) + (wv << 1) + (hi >> 1));
        __hip_atomic_store(fb32 + idx, val, __ATOMIC_RELAXED, __HIP_MEMORY_SCOPE_WORKGROUP);
        if (!uniform)
          __hip_atomic_store(sb32 + idx, val, __ATOMIC_RELAXED, __HIP_MEMORY_SCOPE_AGENT);
      }
      asm volatile("s_waitcnt vmcnt(0)" ::: "memory");   // drains the h1 store
      if (lane == 0) {
        const unsigned fv = FMAGIC + s + 1u;
        if (uniform)
          __hip_atomic_store(myF1F, fv, __ATOMIC_RELAXED, __HIP_MEMORY_SCOPE_WORKGROUP);
        else
          __hip_atomic_store(myF1S, fv, __ATOMIC_RELAXED, __HIP_MEMORY_SCOPE_AGENT);
      }
    }
  }

  // ---- epilogue: lane-local finals
  {
    const int b  = (c << 4) + lm;
    const size_t o = (size_t)b * 256 + jg;
    out[o]                  = h0f;   // h_n layer 0
    out[65536 + o]          = h1f;   // h_n layer 1
    out[131072 + o]         = c0;    // c_n layer 0
    out[131072 + 65536 + o] = c1;    // c_n layer 1
  }
}

extern "C" void kernel_launch(void* const* d_in, const int* in_sizes, int n_in,
                              void* d_out, int out_size, void* d_ws, size_t ws_size,
                              hipStream_t stream) {
  const float* x    = (const float*)d_in[0];
  const float* Wih0 = (const float*)d_in[1];
  const float* Whh0 = (const float*)d_in[2];
  const float* bih0 = (const float*)d_in[3];
  const float* bhh0 = (const float*)d_in[4];
  const float* Wih1 = (const float*)d_in[5];
  const float* Whh1 = (const float*)d_in[6];
  const float* bih1 = (const float*)d_in[7];
  const float* bhh1 = (const float*)d_in[8];

  unsigned long long* fastb = (unsigned long long*)d_ws;
  unsigned long long* slowb;
  unsigned *ctrl, *flagF, *flagS;
  if (ws_size >= (1u << 20) + 24576u) {
    slowb = fastb + 65536;                      // @512KB
    ctrl  = (unsigned*)(fastb + 131072);        // @1MB      (272 u32 used; 8KB reserved)
    flagF = ctrl + 2048;                        // @1MB+8KB  (2048 u32)
    flagS = flagF + 2048;                       // @1MB+16KB (2048 u32)
  } else {                                      // compact fallback (uniform path unaffected)
    slowb = fastb;
    ctrl  = (unsigned*)((char*)d_ws + (512u << 10));
    flagF = ctrl + 2048;
    flagS = flagF;
  }

  lstm2_v9<<<256, 256, 0, stream>>>(x, Wih0, Whh0, bih0, bhh0,
                                    Wih1, Whh1, bih1, bhh1,
                                    (float*)d_out, fastb, slowb, ctrl, flagF, flagS);
}